// Round 5
// baseline (681.549 us; speedup 1.0000x reference)
//
#include <hip/hip_runtime.h>

#define BB 64
#define NN 4096
#define MM 128
#define SCALE 0.25f
#define BGRP 8            // b's per block = waves per block
#define NC 2              // n rows per LDS chunk

typedef const __attribute__((address_space(1))) void* gp_t;
typedef __attribute__((address_space(3))) void* lp_t;

// Block: 8 waves, wave i owns b = bgrp*8+i. All waves share LDS-staged w rows.
// Lane l owns m = 2l, 2l+1. Votes live in regs for qk-dot and out-accum.
// ATOMIC=false: epilogue streams per-block partials (contiguous float2 stores,
// no RMW). ATOMIC=true: legacy fallback (coalesced-ish atomics into acc[b]).
template <int NSPLIT, bool ATOMIC>
__global__ __launch_bounds__(512, 4) void caps_fused(const float* __restrict__ x,
                                                     const float* __restrict__ ncv,
                                                     const float* __restrict__ w,
                                                     float* __restrict__ part) {
    constexpr int NR = NN / NSPLIT;
    constexpr int CHUNKS = NR / NC;
    // nsplit in LOW bits: the 8 blocks sharing one w slice get the same
    // blockIdx%8 -> same XCD -> shared L2 image of the slice.
    const int nsplit = blockIdx.x & (NSPLIT - 1);
    const int bgrp   = blockIdx.x / NSPLIT;
    const int wave   = threadIdx.x >> 6;
    const int lane   = threadIdx.x & 63;
    const int b      = bgrp * BGRP + wave;
    const int n0     = nsplit * NR;
    const int m0     = lane * 2;

    __shared__ float lds_w[2][NC * 2048];       // 2 x 16 KB
    __shared__ float lds_p[2][BGRP * NC * 16];  // 2 x 1 KB

    // ncv[b, m0, :], ncv[b, m0+1, :]
    float nc0[16], nc1[16];
    {
        const float4* p0 = (const float4*)(ncv + ((size_t)b * MM + m0) * 16);
        const float4* p1 = (const float4*)(ncv + ((size_t)b * MM + m0 + 1) * 16);
#pragma unroll
        for (int i = 0; i < 4; ++i) {
            float4 t = p0[i];
            nc0[4 * i + 0] = t.x; nc0[4 * i + 1] = t.y; nc0[4 * i + 2] = t.z; nc0[4 * i + 3] = t.w;
            float4 u = p1[i];
            nc1[4 * i + 0] = u.x; nc1[4 * i + 1] = u.y; nc1[4 * i + 2] = u.z; nc1[4 * i + 3] = u.w;
        }
    }

    float oa0[16], oa1[16];
#pragma unroll
    for (int k = 0; k < 16; ++k) { oa0[k] = 0.0f; oa1[k] = 0.0f; }

    auto stage = [&](int c, int buf) {
        const float* wsrc = w + (size_t)(n0 + c * NC) * 2048;
#pragma unroll
        for (int j = 0; j < NC; ++j) {
            const int off = (wave * NC + j) * 256;   // floats
            __builtin_amdgcn_global_load_lds((gp_t)(wsrc + off + lane * 4),
                                             (lp_t)(&lds_w[buf][off]), 16, 0, 0);
        }
        // pose for all 8 b's of this chunk: lane -> b'=lane>>3, quad q=lane&7
        if (wave == 0) {
            const int bp = lane >> 3, q = lane & 7;
            const float* psrc = x + ((size_t)(bgrp * BGRP + bp) * NN + n0 + c * NC) * 16 + q * 4;
            __builtin_amdgcn_global_load_lds((gp_t)psrc, (lp_t)(&lds_p[buf][0]), 16, 0, 0);
        }
    };

    stage(0, 0);
    __syncthreads();

    for (int c = 0; c < CHUNKS; ++c) {
        const int buf = c & 1;
        if (c + 1 < CHUNKS) stage(c + 1, buf ^ 1);
#pragma unroll
        for (int nn = 0; nn < NC; ++nn) {
            const float* wrow = &lds_w[buf][nn * 2048 + m0];
            const float* pt   = &lds_p[buf][wave * (NC * 16) + nn * 16];
            float4 pA = *(const float4*)(pt + 0);
            float4 pB = *(const float4*)(pt + 4);
            float4 pC = *(const float4*)(pt + 8);
            float4 pD = *(const float4*)(pt + 12);
            // votes v[a*4+d] = sum_x pose[a][x] * w[x*4+d]
            float v0[16], v1[16];
#pragma unroll
            for (int d = 0; d < 4; ++d) {
                float2 w0 = *(const float2*)(wrow + (0 * 4 + d) * 128);
                float2 w1 = *(const float2*)(wrow + (1 * 4 + d) * 128);
                float2 w2 = *(const float2*)(wrow + (2 * 4 + d) * 128);
                float2 w3 = *(const float2*)(wrow + (3 * 4 + d) * 128);
                v0[0  + d] = fmaf(pA.x, w0.x, fmaf(pA.y, w1.x, fmaf(pA.z, w2.x, pA.w * w3.x)));
                v1[0  + d] = fmaf(pA.x, w0.y, fmaf(pA.y, w1.y, fmaf(pA.z, w2.y, pA.w * w3.y)));
                v0[4  + d] = fmaf(pB.x, w0.x, fmaf(pB.y, w1.x, fmaf(pB.z, w2.x, pB.w * w3.x)));
                v1[4  + d] = fmaf(pB.x, w0.y, fmaf(pB.y, w1.y, fmaf(pB.z, w2.y, pB.w * w3.y)));
                v0[8  + d] = fmaf(pC.x, w0.x, fmaf(pC.y, w1.x, fmaf(pC.z, w2.x, pC.w * w3.x)));
                v1[8  + d] = fmaf(pC.x, w0.y, fmaf(pC.y, w1.y, fmaf(pC.z, w2.y, pC.w * w3.y)));
                v0[12 + d] = fmaf(pD.x, w0.x, fmaf(pD.y, w1.x, fmaf(pD.z, w2.x, pD.w * w3.x)));
                v1[12 + d] = fmaf(pD.x, w0.y, fmaf(pD.y, w1.y, fmaf(pD.z, w2.y, pD.w * w3.y)));
            }
            // qk = SCALE * <v, nc>
            float qk0 = 0.0f, qk1 = 0.0f;
#pragma unroll
            for (int k = 0; k < 16; ++k) {
                qk0 = fmaf(v0[k], nc0[k], qk0);
                qk1 = fmaf(v1[k], nc1[k], qk1);
            }
            // softmax over 128 m (2/lane); |qk*SCALE| small -> no max-subtract.
            float p0 = __expf(qk0 * SCALE), p1 = __expf(qk1 * SCALE);
            float s = p0 + p1;
#pragma unroll
            for (int off = 32; off; off >>= 1) s += __shfl_xor(s, off);
            float rinv = 1.0f / s;
            float r0 = p0 * rinv, r1 = p1 * rinv;
#pragma unroll
            for (int k = 0; k < 16; ++k) {
                oa0[k] = fmaf(r0, v0[k], oa0[k]);
                oa1[k] = fmaf(r1, v1[k], oa1[k]);
            }
        }
        __syncthreads();
    }

    if constexpr (!ATOMIC) {
        // Streamed partials: part[nsplit][b][k][m]; lane l stores float2 at
        // m=2l -> each instruction writes one contiguous 512B wave-span.
        float* gp = part + (((size_t)nsplit * BB + b) * 16) * MM + m0;
#pragma unroll
        for (int k = 0; k < 16; ++k) {
            float2 st; st.x = oa0[k]; st.y = oa1[k];
            *(float2*)(gp + k * MM) = st;
        }
    } else {
        float* gout = part + (size_t)b * (16 * MM);
#pragma unroll
        for (int k = 0; k < 16; ++k) {
            atomicAdd(gout + k * MM + m0,     oa0[k]);
            atomicAdd(gout + k * MM + m0 + 1, oa1[k]);
        }
    }
}

// Block per b: sum part[ns][b][k][m] over ns (coalesced float2 streams),
// then LayerNorm over k for each m, write out[b][m][k].
template <int NSPLIT>
__global__ __launch_bounds__(1024) void caps_reduce_ln(const float* __restrict__ part,
                                                       const float* __restrict__ gamma,
                                                       const float* __restrict__ beta,
                                                       float* __restrict__ out) {
    const int b = blockIdx.x;
    const int t = threadIdx.x;           // 1024 threads, 2 elements each
    __shared__ float lds[16 * MM];
    const float* p = part + (size_t)b * (16 * MM) + t * 2;
    float sx = 0.0f, sy = 0.0f;
#pragma unroll 4
    for (int ns = 0; ns < NSPLIT; ++ns) {
        float2 v = *(const float2*)(p + (size_t)ns * BB * 16 * MM);
        sx += v.x; sy += v.y;
    }
    lds[t * 2] = sx; lds[t * 2 + 1] = sy;
    __syncthreads();
    if (t < MM) {                        // t = m
        float v[16];
        float mu = 0.0f;
#pragma unroll
        for (int k = 0; k < 16; ++k) { v[k] = lds[k * MM + t]; mu += v[k]; }
        mu *= (1.0f / 16.0f);
        float var = 0.0f;
#pragma unroll
        for (int k = 0; k < 16; ++k) { float d = v[k] - mu; var = fmaf(d, d, var); }
        var *= (1.0f / 16.0f);
        float rs = rsqrtf(var + 1e-5f);
        float4* o = (float4*)(out + ((size_t)b * MM + t) * 16);
#pragma unroll
        for (int i = 0; i < 4; ++i) {
            float4 r;
            r.x = (v[4 * i + 0] - mu) * rs * gamma[4 * i + 0] + beta[4 * i + 0];
            r.y = (v[4 * i + 1] - mu) * rs * gamma[4 * i + 1] + beta[4 * i + 1];
            r.z = (v[4 * i + 2] - mu) * rs * gamma[4 * i + 2] + beta[4 * i + 2];
            r.w = (v[4 * i + 3] - mu) * rs * gamma[4 * i + 3] + beta[4 * i + 3];
            o[i] = r;
        }
    }
}

extern "C" void kernel_launch(void* const* d_in, const int* in_sizes, int n_in,
                              void* d_out, int out_size, void* d_ws, size_t ws_size,
                              hipStream_t stream) {
    const float* x     = (const float*)d_in[0];
    const float* ncv   = (const float*)d_in[1];
    const float* w     = (const float*)d_in[2];
    const float* gamma = (const float*)d_in[3];
    const float* beta  = (const float*)d_in[4];
    float* out = (float*)d_out;
    float* ws  = (float*)d_ws;

    const size_t per_split = (size_t)BB * 16 * MM * sizeof(float);  // 512 KiB

    if (ws_size >= 128 * per_split) {
        // partials path, NSPLIT=128 (67 MB): 1024 blocks, 4/CU, no atomics
        caps_fused<128, false><<<dim3(BGRP * 128), 512, 0, stream>>>(x, ncv, w, ws);
        caps_reduce_ln<128><<<BB, 1024, 0, stream>>>(ws, gamma, beta, out);
    } else if (ws_size >= 64 * per_split) {
        caps_fused<64, false><<<dim3(BGRP * 64), 512, 0, stream>>>(x, ncv, w, ws);
        caps_reduce_ln<64><<<BB, 1024, 0, stream>>>(ws, gamma, beta, out);
    } else {
        // fallback: atomic accumulation into acc[b][k][m] (R4 path)
        hipMemsetAsync(ws, 0, per_split, stream);
        caps_fused<64, true><<<dim3(BGRP * 64), 512, 0, stream>>>(x, ncv, w, ws);
        caps_reduce_ln<1><<<BB, 1024, 0, stream>>>(ws, gamma, beta, out);
    }
}

// Round 6
// 493.212 us; speedup vs baseline: 1.3819x; 1.3819x over previous
//
#include <hip/hip_runtime.h>

#define BB 64
#define NN 4096
#define MM 128
#define SCALE 0.25f
#define BGRP 8            // b's per block = waves per block
#define NC 2              // n rows per LDS chunk
#define NSPLIT 128
#define NR (NN / NSPLIT)  // 32 n-rows per block
#define CHUNKS (NR / NC)  // 16

typedef const __attribute__((address_space(1))) void* gp_t;
typedef __attribute__((address_space(3))) void* lp_t;

// Block: 8 waves, wave i owns b = bgrp*8+i. All waves share LDS-staged w rows.
// Main loop: lane l owns m = 2l, 2l+1 (w reads = one ds_read_b64 per k).
// Epilogue: in-register lane transpose to m = {l, 64+l}, then CONTIGUOUS-lane
// atomicAdd (R2-proven: contiguous-lane atomics merge perfectly at TCC;
// strided lanes amplify ~70x -- R4/R5 evidence).
__global__ __launch_bounds__(512, 4) void caps_fused(const float* __restrict__ x,
                                                     const float* __restrict__ ncv,
                                                     const float* __restrict__ w,
                                                     float* __restrict__ out_acc) {
    // nsplit in LOW bits: blocks sharing a w slice dispatch adjacently
    const int nsplit = blockIdx.x & (NSPLIT - 1);
    const int bgrp   = blockIdx.x / NSPLIT;
    const int wave   = threadIdx.x >> 6;
    const int lane   = threadIdx.x & 63;
    const int b      = bgrp * BGRP + wave;
    const int n0     = nsplit * NR;
    const int m0     = lane * 2;

    __shared__ float lds_w[2][NC * 2048];       // 2 x 16 KB
    __shared__ float lds_p[2][BGRP * NC * 16];  // 2 x 1 KB

    // ncv[b, m0, :], ncv[b, m0+1, :]
    float nc0[16], nc1[16];
    {
        const float4* p0 = (const float4*)(ncv + ((size_t)b * MM + m0) * 16);
        const float4* p1 = (const float4*)(ncv + ((size_t)b * MM + m0 + 1) * 16);
#pragma unroll
        for (int i = 0; i < 4; ++i) {
            float4 t = p0[i];
            nc0[4 * i + 0] = t.x; nc0[4 * i + 1] = t.y; nc0[4 * i + 2] = t.z; nc0[4 * i + 3] = t.w;
            float4 u = p1[i];
            nc1[4 * i + 0] = u.x; nc1[4 * i + 1] = u.y; nc1[4 * i + 2] = u.z; nc1[4 * i + 3] = u.w;
        }
    }

    float oa0[16], oa1[16];
#pragma unroll
    for (int k = 0; k < 16; ++k) { oa0[k] = 0.0f; oa1[k] = 0.0f; }

    auto stage = [&](int c, int buf) {
        const float* wsrc = w + (size_t)(n0 + c * NC) * 2048;
#pragma unroll
        for (int j = 0; j < NC; ++j) {
            const int off = (wave * NC + j) * 256;   // floats
            __builtin_amdgcn_global_load_lds((gp_t)(wsrc + off + lane * 4),
                                             (lp_t)(&lds_w[buf][off]), 16, 0, 0);
        }
        // pose for all 8 b's of this chunk: lane -> b'=lane>>3, quad q=lane&7
        if (wave == 0) {
            const int bp = lane >> 3, q = lane & 7;
            const float* psrc = x + ((size_t)(bgrp * BGRP + bp) * NN + n0 + c * NC) * 16 + q * 4;
            __builtin_amdgcn_global_load_lds((gp_t)psrc, (lp_t)(&lds_p[buf][0]), 16, 0, 0);
        }
    };

    stage(0, 0);
    __syncthreads();

    for (int c = 0; c < CHUNKS; ++c) {
        const int buf = c & 1;
        if (c + 1 < CHUNKS) stage(c + 1, buf ^ 1);
#pragma unroll
        for (int nn = 0; nn < NC; ++nn) {
            const float* wrow = &lds_w[buf][nn * 2048 + m0];
            const float* pt   = &lds_p[buf][wave * (NC * 16) + nn * 16];
            float4 pA = *(const float4*)(pt + 0);
            float4 pB = *(const float4*)(pt + 4);
            float4 pC = *(const float4*)(pt + 8);
            float4 pD = *(const float4*)(pt + 12);
            // votes v[a*4+d] = sum_x pose[a][x] * w[x*4+d]
            float v0[16], v1[16];
#pragma unroll
            for (int d = 0; d < 4; ++d) {
                float2 w0 = *(const float2*)(wrow + (0 * 4 + d) * 128);
                float2 w1 = *(const float2*)(wrow + (1 * 4 + d) * 128);
                float2 w2 = *(const float2*)(wrow + (2 * 4 + d) * 128);
                float2 w3 = *(const float2*)(wrow + (3 * 4 + d) * 128);
                v0[0  + d] = fmaf(pA.x, w0.x, fmaf(pA.y, w1.x, fmaf(pA.z, w2.x, pA.w * w3.x)));
                v1[0  + d] = fmaf(pA.x, w0.y, fmaf(pA.y, w1.y, fmaf(pA.z, w2.y, pA.w * w3.y)));
                v0[4  + d] = fmaf(pB.x, w0.x, fmaf(pB.y, w1.x, fmaf(pB.z, w2.x, pB.w * w3.x)));
                v1[4  + d] = fmaf(pB.x, w0.y, fmaf(pB.y, w1.y, fmaf(pB.z, w2.y, pB.w * w3.y)));
                v0[8  + d] = fmaf(pC.x, w0.x, fmaf(pC.y, w1.x, fmaf(pC.z, w2.x, pC.w * w3.x)));
                v1[8  + d] = fmaf(pC.x, w0.y, fmaf(pC.y, w1.y, fmaf(pC.z, w2.y, pC.w * w3.y)));
                v0[12 + d] = fmaf(pD.x, w0.x, fmaf(pD.y, w1.x, fmaf(pD.z, w2.x, pD.w * w3.x)));
                v1[12 + d] = fmaf(pD.x, w0.y, fmaf(pD.y, w1.y, fmaf(pD.z, w2.y, pD.w * w3.y)));
            }
            // qk = SCALE * <v, nc>
            float qk0 = 0.0f, qk1 = 0.0f;
#pragma unroll
            for (int k = 0; k < 16; ++k) {
                qk0 = fmaf(v0[k], nc0[k], qk0);
                qk1 = fmaf(v1[k], nc1[k], qk1);
            }
            // softmax over 128 m (2/lane); |qk*SCALE| small -> no max-subtract.
            float p0 = __expf(qk0 * SCALE), p1 = __expf(qk1 * SCALE);
            float s = p0 + p1;
#pragma unroll
            for (int off = 32; off; off >>= 1) s += __shfl_xor(s, off);
            float rinv = 1.0f / s;
            float r0 = p0 * rinv, r1 = p1 * rinv;
#pragma unroll
            for (int k = 0; k < 16; ++k) {
                oa0[k] = fmaf(r0, v0[k], oa0[k]);
                oa1[k] = fmaf(r1, v1[k], oa1[k]);
            }
        }
        __syncthreads();
    }

    // In-register lane transpose: lane l takes ownership of m=l and m=64+l.
    //   m=l     lived at lane l>>1,      array (l&1 ? oa1 : oa0)
    //   m=64+l  lived at lane 32+(l>>1), array (l&1 ? oa1 : oa0)
    float na[16], nb[16];
    const int src0 = lane >> 1;
    const int src1 = 32 + (lane >> 1);
    const bool odd = lane & 1;
#pragma unroll
    for (int k = 0; k < 16; ++k) {
        float a0 = __shfl(oa0[k], src0);
        float a1 = __shfl(oa1[k], src0);
        float b0 = __shfl(oa0[k], src1);
        float b1 = __shfl(oa1[k], src1);
        na[k] = odd ? a1 : a0;
        nb[k] = odd ? b1 : b0;
    }
    // Contiguous-lane atomics: each instruction = 64 lanes x 4B contiguous.
    float* gout = out_acc + (size_t)b * (16 * MM);
#pragma unroll
    for (int k = 0; k < 16; ++k) {
        atomicAdd(gout + k * MM + lane,      na[k]);
        atomicAdd(gout + k * MM + 64 + lane, nb[k]);
    }
}

// Block per b. acc[b][k][m] -> LDS -> thread-per-m LayerNorm -> out[b][m][k].
__global__ __launch_bounds__(128) void caps_ln(const float* __restrict__ acc,
                                               const float* __restrict__ gamma,
                                               const float* __restrict__ beta,
                                               float* __restrict__ out) {
    const int b = blockIdx.x;
    const int t = threadIdx.x;   // = m
    __shared__ float lds[16 * MM];
    const float* gacc = acc + (size_t)b * (16 * MM);
#pragma unroll
    for (int j = 0; j < 4; ++j) {
        const int idx = j * 512 + t * 4;
        *(float4*)(lds + idx) = *(const float4*)(gacc + idx);   // coalesced
    }
    __syncthreads();
    float v[16];
    float mu = 0.0f;
#pragma unroll
    for (int k = 0; k < 16; ++k) { v[k] = lds[k * MM + t]; mu += v[k]; }  // 2 lanes/bank: free
    mu *= (1.0f / 16.0f);
    float var = 0.0f;
#pragma unroll
    for (int k = 0; k < 16; ++k) { float d = v[k] - mu; var = fmaf(d, d, var); }
    var *= (1.0f / 16.0f);
    float rs = rsqrtf(var + 1e-5f);
    float4* o = (float4*)(out + ((size_t)b * MM + t) * 16);
#pragma unroll
    for (int i = 0; i < 4; ++i) {
        float4 r;
        r.x = (v[4 * i + 0] - mu) * rs * gamma[4 * i + 0] + beta[4 * i + 0];
        r.y = (v[4 * i + 1] - mu) * rs * gamma[4 * i + 1] + beta[4 * i + 1];
        r.z = (v[4 * i + 2] - mu) * rs * gamma[4 * i + 2] + beta[4 * i + 2];
        r.w = (v[4 * i + 3] - mu) * rs * gamma[4 * i + 3] + beta[4 * i + 3];
        o[i] = r;
    }
}

extern "C" void kernel_launch(void* const* d_in, const int* in_sizes, int n_in,
                              void* d_out, int out_size, void* d_ws, size_t ws_size,
                              hipStream_t stream) {
    const float* x     = (const float*)d_in[0];
    const float* ncv   = (const float*)d_in[1];
    const float* w     = (const float*)d_in[2];
    const float* gamma = (const float*)d_in[3];
    const float* beta  = (const float*)d_in[4];
    float* out = (float*)d_out;
    float* acc = (float*)d_ws;   // acc[b][k][m] fp32 = 512 KiB

    hipMemsetAsync(acc, 0, (size_t)BB * 16 * MM * sizeof(float), stream);

    caps_fused<<<dim3(BGRP * NSPLIT), 512, 0, stream>>>(x, ncv, w, acc);  // 1024 blocks, 4/CU

    caps_ln<<<BB, 128, 0, stream>>>(acc, gamma, beta, out);
}